// Round 3
// baseline (355.191 us; speedup 1.0000x reference)
//
#include <hip/hip_runtime.h>
#include <stdint.h>

#define CH 64
#define NPTS 500000
#define NW 7813                // ceil(NPTS/64) wave-jobs: 64 points per wave
#define NSTEP 12
#define BLK 256
#define WPB (BLK / 64)         // waves per block

typedef float floatx16 __attribute__((ext_vector_type(16)));
typedef __bf16 bf16x8 __attribute__((ext_vector_type(8)));

// pack two fp32 into (bf16(even) | bf16(odd)<<16) by byte-perm truncation
__device__ __forceinline__ unsigned pk(float odd, float even) {
    return __builtin_amdgcn_perm(__float_as_uint(odd), __float_as_uint(even), 0x07060302u);
}
// top-16-bit truncation of x as a float (the "hi" bf16 part, exactly representable)
__device__ __forceinline__ float hif(float x) {
    return __uint_as_float(__float_as_uint(x) & 0xffff0000u);
}

struct U16 { unsigned a, b, c, d; };
__device__ __forceinline__ bf16x8 asb4(unsigned x0, unsigned x1, unsigned x2, unsigned x3) {
    U16 t{x0, x1, x2, x3};
    return __builtin_bit_cast(bf16x8, t);
}
__device__ __forceinline__ bf16x8 asbu4(uint4 v) {
    return __builtin_bit_cast(bf16x8, v);
}

// async global->LDS, 16B per lane; lds ptr must be wave-uniform (HW scatters +lane*16)
typedef __attribute__((address_space(3))) void lds_void;
typedef const __attribute__((address_space(1))) void gm_void;
__device__ __forceinline__ void gload_lds16(const void* g, void* l) {
    __builtin_amdgcn_global_load_lds((gm_void*)g, (lds_void*)l, 16, 0, 0);
}

#define MFMA_B(A, Bv, C) __builtin_amdgcn_mfma_f32_32x32x16_bf16(asbu4(A), Bv, C, 0, 0, 0)

// ---------------------------------------------------------------------------
// Prep kernel: W[step][k][c_out] -> bf16 hi/lo A-fragments with the bit2<->bit3
// column permutation, in lane-contiguous per-step 16 KB groups.
// flat uint4 idx = s*1024 + ((pl*2+mt)*4+q)*64 + lane
// ---------------------------------------------------------------------------
__global__ void prep_weights(const float* __restrict__ W0,
                             const float* __restrict__ W1,
                             const float* __restrict__ W2,
                             uint4* __restrict__ wsA) {
    const int g  = blockIdx.x * blockDim.x + threadIdx.x;   // 0..12287
    const int mp = g & 31;
    const int h  = (g >> 5) & 1;
    const int q  = (g >> 6) & 3;
    const int mt = (g >> 8) & 1;
    const int pl = (g >> 9) & 1;
    const int s  = g >> 10;
    const float* Wb = (s % 3 == 0) ? W0 : ((s % 3 == 1) ? W1 : W2);
    const float* Ws = Wb + (s / 3) * CH * CH;
    const int m   = mt * 32 + mp;
    const int col = (m & ~12) | ((m & 4) << 1) | ((m & 8) >> 1);  // swap bits 2,3
    unsigned o[4];
    #pragma unroll
    for (int d = 0; d < 4; ++d) {
        float e = Ws[(16 * q + 8 * h + 2 * d) * CH + col];
        float v = Ws[(16 * q + 8 * h + 2 * d + 1) * CH + col];
        if (pl) { e = e - hif(e); v = v - hif(v); }   // lo plane
        o[d] = pk(v, e);
    }
    wsA[g] = make_uint4(o[0], o[1], o[2], o[3]);
}

// ---------------------------------------------------------------------------
// Main kernel: one wave = 64 points (2 x 32-pt tiles), register-resident
// 12-GEMM chain. Each 16 KB/step A-fragment read from LDS now feeds TWO
// point-tiles -> LDS read traffic per point halved (3 GB -> 1.5 GB total),
// per-point loop overhead halved; MFMA/point unchanged (48 MFMA/wave-step).
// launch_bounds(256,3): live set ~= acc 64 + B 64 + A 32 + misc ~10 = 170
// = the (256,3) budget. (256,4)=128 would force spill; (256,5) spilled
// catastrophically in round 1. Spill tripwire: WRITE_SIZE >> 125 MB.
// s-loop unrolled by 6 (= lcm(2,3)) so LDS buffer parity, bias select and
// relu flag are compile-time while body stays under the 32 KB I-cache.
// ---------------------------------------------------------------------------
__global__ __launch_bounds__(BLK, 3) void mlp12_mfma(
    const float* __restrict__ feat,
    const uint4* __restrict__ wsA,
    const float* __restrict__ b0,
    const float* __restrict__ b1,
    const float* __restrict__ b2,
    float* __restrict__ out)
{
    __shared__ uint4 sA[2][1024];   // 2 x 16 KB weight-fragment buffers

    const int tid  = threadIdx.x;
    const int lane = tid & 63;
    const int wv   = tid >> 6;
    int wid = blockIdx.x * WPB + wv;
    if (wid > NW - 1) wid = NW - 1;     // tail waves redo last job (benign)
    const int n = lane & 31;            // point within tile (MFMA col)
    const int h = lane >> 5;            // half-wave = k/channel bit3
    const size_t row0 = ((size_t)wid * 64 + n) * CH;
    // last job covers only 32 points (NPTS = 7812*64 + 32): duplicate tile0
    const size_t row1 = (wid == NW - 1) ? row0 : row0 + (size_t)32 * CH;

    // stage step-0 fragments into sA[0]: each thread issues 4 x 16B DMA
    {
        const char* g = (const char*)wsA;
        #pragma unroll
        for (int c = 0; c < 4; ++c)
            gload_lds16(g + (wv * 4 + c) * 1024 + lane * 16,
                        (char*)&sA[0][0] + (wv * 4 + c) * 1024);
    }

    // build step-0 B fragments for both tiles straight from feature loads
    // (per-q, short liveness; VALU overlaps the staging DMA drain)
    unsigned Bhi[2][4][4], Blo[2][4][4];
    {
        const float* f0 = feat + row0 + 8 * h;
        const float* f1 = feat + row1 + 8 * h;
        #pragma unroll
        for (int q = 0; q < 4; ++q) {
            float4 va = *(const float4*)(f0 + 16 * q);
            float4 vb = *(const float4*)(f0 + 16 * q + 4);
            Bhi[0][q][0] = pk(va.y, va.x);  Bhi[0][q][1] = pk(va.w, va.z);
            Bhi[0][q][2] = pk(vb.y, vb.x);  Bhi[0][q][3] = pk(vb.w, vb.z);
            Blo[0][q][0] = pk(va.y - hif(va.y), va.x - hif(va.x));
            Blo[0][q][1] = pk(va.w - hif(va.w), va.z - hif(va.z));
            Blo[0][q][2] = pk(vb.y - hif(vb.y), vb.x - hif(vb.x));
            Blo[0][q][3] = pk(vb.w - hif(vb.w), vb.z - hif(vb.z));
            float4 vc = *(const float4*)(f1 + 16 * q);
            float4 vd = *(const float4*)(f1 + 16 * q + 4);
            Bhi[1][q][0] = pk(vc.y, vc.x);  Bhi[1][q][1] = pk(vc.w, vc.z);
            Bhi[1][q][2] = pk(vd.y, vd.x);  Bhi[1][q][3] = pk(vd.w, vd.z);
            Blo[1][q][0] = pk(vc.y - hif(vc.y), vc.x - hif(vc.x));
            Blo[1][q][1] = pk(vc.w - hif(vc.w), vc.z - hif(vc.z));
            Blo[1][q][2] = pk(vd.y - hif(vd.y), vd.x - hif(vd.x));
            Blo[1][q][3] = pk(vd.w - hif(vd.w), vd.z - hif(vd.z));
        }
    }
    __syncthreads();   // drains vmcnt -> sA[0] ready

    floatx16 ac00, ac01, ac10, ac11;   // [tile][row-half(32ch)]

    #pragma unroll 1
    for (int k = 0; k < 2; ++k) {
        const char*  gk  = (const char*)wsA + (size_t)k * 6 * 16384;
        const float* bb0 = b0 + 2 * k * CH;
        const float* bb1 = b1 + 2 * k * CH;
        const float* bb2 = b2 + 2 * k * CH;
        #pragma unroll
        for (int j = 0; j < 6; ++j) {
            const int s = 6 * k + j;
            const int b = j & 1;        // 6k even -> parity is compile-time

            // prefetch step s+1 into the buffer freed by the previous barrier
            if (s + 1 < NSTEP) {
                const char* g = gk + (size_t)(j + 1) * 16384;
                #pragma unroll
                for (int c = 0; c < 4; ++c)
                    gload_lds16(g + (wv * 4 + c) * 1024 + lane * 16,
                                (char*)&sA[1 - b][0] + (wv * 4 + c) * 1024);
            }

            const uint4* base = &sA[b][0];

            // issue first A chunk (q=0) early: ds_read latency hides under B-build
            uint4 Acur[4], Anx[4];
            #pragma unroll
            for (int t = 0; t < 4; ++t) Acur[t] = base[(t * 4 + 0) * 64 + lane];

            // ---- build B fragments from prev accs (step 0 built in prologue)
            if (s > 0) {
                const bool relu = (j % 3 == 2);  // prev step had ReLU
                #pragma unroll
                for (int q = 0; q < 4; ++q) {
                    const int rr = q & 1;
                    #pragma unroll
                    for (int d = 0; d < 4; ++d) {
                        float e, o;
                        if (q < 2) { e = ac00[8*rr+2*d]; o = ac00[8*rr+2*d+1]; }
                        else       { e = ac01[8*rr+2*d]; o = ac01[8*rr+2*d+1]; }
                        if (relu) { e = fmaxf(e, 0.f); o = fmaxf(o, 0.f); }
                        Bhi[0][q][d] = pk(o, e);
                        Blo[0][q][d] = pk(o - hif(o), e - hif(e));
                    }
                }
                #pragma unroll
                for (int q = 0; q < 4; ++q) {
                    const int rr = q & 1;
                    #pragma unroll
                    for (int d = 0; d < 4; ++d) {
                        float e, o;
                        if (q < 2) { e = ac10[8*rr+2*d]; o = ac10[8*rr+2*d+1]; }
                        else       { e = ac11[8*rr+2*d]; o = ac11[8*rr+2*d+1]; }
                        if (relu) { e = fmaxf(e, 0.f); o = fmaxf(o, 0.f); }
                        Bhi[1][q][d] = pk(o, e);
                        Blo[1][q][d] = pk(o - hif(o), e - hif(e));
                    }
                }
            }

            // ---- init accumulators with bias (bias depends on channel only:
            // both point-tiles share the same loaded values)
            {
                const float* bs = ((j % 3 == 0) ? bb0 : (j % 3 == 1) ? bb1 : bb2)
                                  + (j / 3) * CH;
                #pragma unroll
                for (int rq = 0; rq < 4; ++rq) {
                    const int off = 16 * (rq >> 1) + 8 * h + 4 * (rq & 1);
                    float4 v0 = *(const float4*)(bs + off);
                    float4 v1 = *(const float4*)(bs + 32 + off);
                    ac00[4*rq+0] = v0.x; ac00[4*rq+1] = v0.y;
                    ac00[4*rq+2] = v0.z; ac00[4*rq+3] = v0.w;
                    ac10[4*rq+0] = v0.x; ac10[4*rq+1] = v0.y;
                    ac10[4*rq+2] = v0.z; ac10[4*rq+3] = v0.w;
                    ac01[4*rq+0] = v1.x; ac01[4*rq+1] = v1.y;
                    ac01[4*rq+2] = v1.z; ac01[4*rq+3] = v1.w;
                    ac11[4*rq+0] = v1.x; ac11[4*rq+1] = v1.y;
                    ac11[4*rq+2] = v1.z; ac11[4*rq+3] = v1.w;
                }
            }

            // ---- 48 MFMAs: each A chunk feeds both point-tiles (4 indep chains)
            #pragma unroll
            for (int q = 0; q < 4; ++q) {
                if (q < 3) {
                    #pragma unroll
                    for (int t = 0; t < 4; ++t) Anx[t] = base[(t * 4 + q + 1) * 64 + lane];
                }
                bf16x8 b0h = asb4(Bhi[0][q][0], Bhi[0][q][1], Bhi[0][q][2], Bhi[0][q][3]);
                bf16x8 b0l = asb4(Blo[0][q][0], Blo[0][q][1], Blo[0][q][2], Blo[0][q][3]);
                bf16x8 b1h = asb4(Bhi[1][q][0], Bhi[1][q][1], Bhi[1][q][2], Bhi[1][q][3]);
                bf16x8 b1l = asb4(Blo[1][q][0], Blo[1][q][1], Blo[1][q][2], Blo[1][q][3]);
                ac00 = MFMA_B(Acur[0], b0h, ac00);   // hi-W x hi-X
                ac01 = MFMA_B(Acur[1], b0h, ac01);
                ac10 = MFMA_B(Acur[0], b1h, ac10);
                ac11 = MFMA_B(Acur[1], b1h, ac11);
                ac00 = MFMA_B(Acur[2], b0h, ac00);   // lo-W x hi-X
                ac01 = MFMA_B(Acur[3], b0h, ac01);
                ac10 = MFMA_B(Acur[2], b1h, ac10);
                ac11 = MFMA_B(Acur[3], b1h, ac11);
                ac00 = MFMA_B(Acur[0], b0l, ac00);   // hi-W x lo-X
                ac01 = MFMA_B(Acur[1], b0l, ac01);
                ac10 = MFMA_B(Acur[0], b1l, ac10);
                ac11 = MFMA_B(Acur[1], b1l, ac11);
                #pragma unroll
                for (int t = 0; t < 4; ++t) Acur[t] = Anx[t];
            }

            __syncthreads();  // all waves done with sA[b]; prefetch of s+1 drained
        }
    }

    // ---- store step-11 output for both tiles
    float* o0 = out + row0;
    float* o1 = out + row1;
    #pragma unroll
    for (int rq = 0; rq < 4; ++rq) {
        const int off = 16 * (rq >> 1) + 8 * h + 4 * (rq & 1);
        float4 v;
        v.x = ac00[4*rq+0]; v.y = ac00[4*rq+1]; v.z = ac00[4*rq+2]; v.w = ac00[4*rq+3];
        *(float4*)(o0 + off) = v;
        v.x = ac01[4*rq+0]; v.y = ac01[4*rq+1]; v.z = ac01[4*rq+2]; v.w = ac01[4*rq+3];
        *(float4*)(o0 + 32 + off) = v;
        v.x = ac10[4*rq+0]; v.y = ac10[4*rq+1]; v.z = ac10[4*rq+2]; v.w = ac10[4*rq+3];
        *(float4*)(o1 + off) = v;
        v.x = ac11[4*rq+0]; v.y = ac11[4*rq+1]; v.z = ac11[4*rq+2]; v.w = ac11[4*rq+3];
        *(float4*)(o1 + 32 + off) = v;
    }
}

extern "C" void kernel_launch(void* const* d_in, const int* in_sizes, int n_in,
                              void* d_out, int out_size, void* d_ws, size_t ws_size,
                              hipStream_t stream) {
    const float* feat = (const float*)d_in[0];
    // d_in[1] = points, d_in[2] = nuv — dead inputs
    const float* W0 = (const float*)d_in[3];
    const float* b0 = (const float*)d_in[4];
    const float* W1 = (const float*)d_in[5];
    const float* b1 = (const float*)d_in[6];
    const float* W2 = (const float*)d_in[7];
    const float* b2 = (const float*)d_in[8];
    float* out = (float*)d_out;
    uint4* wsA = (uint4*)d_ws;   // 12288 * 16B = 192 KiB of scratch

    prep_weights<<<48, 256, 0, stream>>>(W0, W1, W2, wsA);

    const int grid = (NW + WPB - 1) / WPB;
    mlp12_mfma<<<grid, BLK, 0, stream>>>(feat, wsA, b0, b1, b2, out);
}

// Round 4
// 338.977 us; speedup vs baseline: 1.0478x; 1.0478x over previous
//
#include <hip/hip_runtime.h>
#include <stdint.h>

#define CH 64
#define NPTS 500000
#define NW 7813                // ceil(NPTS/64) wave-jobs: 64 points per wave
#define NSTEP 12
#define BLK 256
#define WPB (BLK / 64)         // waves per block

typedef float floatx16 __attribute__((ext_vector_type(16)));
typedef __bf16 bf16x8 __attribute__((ext_vector_type(8)));

// pack two fp32 into (bf16(even) | bf16(odd)<<16) by byte-perm truncation
__device__ __forceinline__ unsigned pk(float odd, float even) {
    return __builtin_amdgcn_perm(__float_as_uint(odd), __float_as_uint(even), 0x07060302u);
}
// top-16-bit truncation of x as a float (the "hi" bf16 part, exactly representable)
__device__ __forceinline__ float hif(float x) {
    return __uint_as_float(__float_as_uint(x) & 0xffff0000u);
}

struct U16 { unsigned a, b, c, d; };
__device__ __forceinline__ bf16x8 asb4(unsigned x0, unsigned x1, unsigned x2, unsigned x3) {
    U16 t{x0, x1, x2, x3};
    return __builtin_bit_cast(bf16x8, t);
}
__device__ __forceinline__ bf16x8 asbu4(uint4 v) {
    return __builtin_bit_cast(bf16x8, v);
}

// async global->LDS, 16B per lane; lds ptr must be wave-uniform (HW scatters +lane*16)
typedef __attribute__((address_space(3))) void lds_void;
typedef const __attribute__((address_space(1))) void gm_void;
__device__ __forceinline__ void gload_lds16(const void* g, void* l) {
    __builtin_amdgcn_global_load_lds((gm_void*)g, (lds_void*)l, 16, 0, 0);
}

#define MFMA_B(A, Bv, C) __builtin_amdgcn_mfma_f32_32x32x16_bf16(asbu4(A), Bv, C, 0, 0, 0)

// ---------------------------------------------------------------------------
// Prep kernel: W[step][k][c_out] -> bf16 hi/lo A-fragments with the bit2<->bit3
// column permutation, in lane-contiguous per-step 16 KB groups.
// flat uint4 idx = s*1024 + ((pl*2+mt)*4+q)*64 + lane
// ---------------------------------------------------------------------------
__global__ void prep_weights(const float* __restrict__ W0,
                             const float* __restrict__ W1,
                             const float* __restrict__ W2,
                             uint4* __restrict__ wsA) {
    const int g  = blockIdx.x * blockDim.x + threadIdx.x;   // 0..12287
    const int mp = g & 31;
    const int h  = (g >> 5) & 1;
    const int q  = (g >> 6) & 3;
    const int mt = (g >> 8) & 1;
    const int pl = (g >> 9) & 1;
    const int s  = g >> 10;
    const float* Wb = (s % 3 == 0) ? W0 : ((s % 3 == 1) ? W1 : W2);
    const float* Ws = Wb + (s / 3) * CH * CH;
    const int m   = mt * 32 + mp;
    const int col = (m & ~12) | ((m & 4) << 1) | ((m & 8) >> 1);  // swap bits 2,3
    unsigned o[4];
    #pragma unroll
    for (int d = 0; d < 4; ++d) {
        float e = Ws[(16 * q + 8 * h + 2 * d) * CH + col];
        float v = Ws[(16 * q + 8 * h + 2 * d + 1) * CH + col];
        if (pl) { e = e - hif(e); v = v - hif(v); }   // lo plane
        o[d] = pk(v, e);
    }
    wsA[g] = make_uint4(o[0], o[1], o[2], o[3]);
}

// ---------------------------------------------------------------------------
// Main kernel: one wave = 64 points (2 x 32-pt tiles), register-resident
// 12-GEMM chain. Each 16 KB/step A-fragment LDS read feeds TWO point-tiles
// (LDS read/point halved, 4 independent MFMA chains per step).
// REGISTER HISTORY (hard-won): live set = acc 64 + B 64 + A 32 + bias/addr
// ~45 = ~205 regs.  (256,5)=102: massive spill (R1).  (256,3)=170: spilled
// ~140 MB scratch traffic, MfmaUtil 33% (R3).  (256,2)=256: fits.  The
// occupancy loss (2 waves/SIMD) is paid for by the 48-MFMA burst (~1550 cy)
// covering the other wave's VALU phase (~800 cy) + barrier drain.
// Spill tripwire: WRITE_SIZE >> 125 MB or FETCH >> 64 MB.
// s-loop unrolled by 6 (= lcm(2,3)) so LDS buffer parity, bias select and
// relu flag are compile-time while body stays under the 32 KB I-cache.
// ---------------------------------------------------------------------------
__global__ __launch_bounds__(BLK, 2) void mlp12_mfma(
    const float* __restrict__ feat,
    const uint4* __restrict__ wsA,
    const float* __restrict__ b0,
    const float* __restrict__ b1,
    const float* __restrict__ b2,
    float* __restrict__ out)
{
    __shared__ uint4 sA[2][1024];   // 2 x 16 KB weight-fragment buffers

    const int tid  = threadIdx.x;
    const int lane = tid & 63;
    const int wv   = tid >> 6;
    int wid = blockIdx.x * WPB + wv;
    if (wid > NW - 1) wid = NW - 1;     // tail waves redo last job (benign)
    const int n = lane & 31;            // point within tile (MFMA col)
    const int h = lane >> 5;            // half-wave = k/channel bit3
    const size_t row0 = ((size_t)wid * 64 + n) * CH;
    // last job covers only 32 points (NPTS = 7812*64 + 32): duplicate tile0
    const size_t row1 = (wid == NW - 1) ? row0 : row0 + (size_t)32 * CH;

    // stage step-0 fragments into sA[0]: each thread issues 4 x 16B DMA
    {
        const char* g = (const char*)wsA;
        #pragma unroll
        for (int c = 0; c < 4; ++c)
            gload_lds16(g + (wv * 4 + c) * 1024 + lane * 16,
                        (char*)&sA[0][0] + (wv * 4 + c) * 1024);
    }

    // build step-0 B fragments for both tiles straight from feature loads
    // (per-q, short liveness; VALU overlaps the staging DMA drain)
    unsigned Bhi[2][4][4], Blo[2][4][4];
    {
        const float* f0 = feat + row0 + 8 * h;
        const float* f1 = feat + row1 + 8 * h;
        #pragma unroll
        for (int q = 0; q < 4; ++q) {
            float4 va = *(const float4*)(f0 + 16 * q);
            float4 vb = *(const float4*)(f0 + 16 * q + 4);
            Bhi[0][q][0] = pk(va.y, va.x);  Bhi[0][q][1] = pk(va.w, va.z);
            Bhi[0][q][2] = pk(vb.y, vb.x);  Bhi[0][q][3] = pk(vb.w, vb.z);
            Blo[0][q][0] = pk(va.y - hif(va.y), va.x - hif(va.x));
            Blo[0][q][1] = pk(va.w - hif(va.w), va.z - hif(va.z));
            Blo[0][q][2] = pk(vb.y - hif(vb.y), vb.x - hif(vb.x));
            Blo[0][q][3] = pk(vb.w - hif(vb.w), vb.z - hif(vb.z));
            float4 vc = *(const float4*)(f1 + 16 * q);
            float4 vd = *(const float4*)(f1 + 16 * q + 4);
            Bhi[1][q][0] = pk(vc.y, vc.x);  Bhi[1][q][1] = pk(vc.w, vc.z);
            Bhi[1][q][2] = pk(vd.y, vd.x);  Bhi[1][q][3] = pk(vd.w, vd.z);
            Blo[1][q][0] = pk(vc.y - hif(vc.y), vc.x - hif(vc.x));
            Blo[1][q][1] = pk(vc.w - hif(vc.w), vc.z - hif(vc.z));
            Blo[1][q][2] = pk(vd.y - hif(vd.y), vd.x - hif(vd.x));
            Blo[1][q][3] = pk(vd.w - hif(vd.w), vd.z - hif(vd.z));
        }
    }
    __syncthreads();   // drains vmcnt -> sA[0] ready

    floatx16 ac00, ac01, ac10, ac11;   // [tile][row-half(32ch)]

    #pragma unroll 1
    for (int k = 0; k < 2; ++k) {
        const char*  gk  = (const char*)wsA + (size_t)k * 6 * 16384;
        const float* bb0 = b0 + 2 * k * CH;
        const float* bb1 = b1 + 2 * k * CH;
        const float* bb2 = b2 + 2 * k * CH;
        #pragma unroll
        for (int j = 0; j < 6; ++j) {
            const int s = 6 * k + j;
            const int b = j & 1;        // 6k even -> parity is compile-time

            // prefetch step s+1 into the buffer freed by the previous barrier
            if (s + 1 < NSTEP) {
                const char* g = gk + (size_t)(j + 1) * 16384;
                #pragma unroll
                for (int c = 0; c < 4; ++c)
                    gload_lds16(g + (wv * 4 + c) * 1024 + lane * 16,
                                (char*)&sA[1 - b][0] + (wv * 4 + c) * 1024);
            }

            const uint4* base = &sA[b][0];

            // issue first A chunk (q=0) early: ds_read latency hides under B-build
            uint4 Acur[4], Anx[4];
            #pragma unroll
            for (int t = 0; t < 4; ++t) Acur[t] = base[(t * 4 + 0) * 64 + lane];

            // ---- build B fragments from prev accs (step 0 built in prologue)
            if (s > 0) {
                const bool relu = (j % 3 == 2);  // prev step had ReLU
                #pragma unroll
                for (int q = 0; q < 4; ++q) {
                    const int rr = q & 1;
                    #pragma unroll
                    for (int d = 0; d < 4; ++d) {
                        float e, o;
                        if (q < 2) { e = ac00[8*rr+2*d]; o = ac00[8*rr+2*d+1]; }
                        else       { e = ac01[8*rr+2*d]; o = ac01[8*rr+2*d+1]; }
                        if (relu) { e = fmaxf(e, 0.f); o = fmaxf(o, 0.f); }
                        Bhi[0][q][d] = pk(o, e);
                        Blo[0][q][d] = pk(o - hif(o), e - hif(e));
                    }
                }
                #pragma unroll
                for (int q = 0; q < 4; ++q) {
                    const int rr = q & 1;
                    #pragma unroll
                    for (int d = 0; d < 4; ++d) {
                        float e, o;
                        if (q < 2) { e = ac10[8*rr+2*d]; o = ac10[8*rr+2*d+1]; }
                        else       { e = ac11[8*rr+2*d]; o = ac11[8*rr+2*d+1]; }
                        if (relu) { e = fmaxf(e, 0.f); o = fmaxf(o, 0.f); }
                        Bhi[1][q][d] = pk(o, e);
                        Blo[1][q][d] = pk(o - hif(o), e - hif(e));
                    }
                }
            }

            // ---- init accumulators with bias (bias depends on channel only:
            // both point-tiles share the same loaded values)
            {
                const float* bs = ((j % 3 == 0) ? bb0 : (j % 3 == 1) ? bb1 : bb2)
                                  + (j / 3) * CH;
                #pragma unroll
                for (int rq = 0; rq < 4; ++rq) {
                    const int off = 16 * (rq >> 1) + 8 * h + 4 * (rq & 1);
                    float4 v0 = *(const float4*)(bs + off);
                    float4 v1 = *(const float4*)(bs + 32 + off);
                    ac00[4*rq+0] = v0.x; ac00[4*rq+1] = v0.y;
                    ac00[4*rq+2] = v0.z; ac00[4*rq+3] = v0.w;
                    ac10[4*rq+0] = v0.x; ac10[4*rq+1] = v0.y;
                    ac10[4*rq+2] = v0.z; ac10[4*rq+3] = v0.w;
                    ac01[4*rq+0] = v1.x; ac01[4*rq+1] = v1.y;
                    ac01[4*rq+2] = v1.z; ac01[4*rq+3] = v1.w;
                    ac11[4*rq+0] = v1.x; ac11[4*rq+1] = v1.y;
                    ac11[4*rq+2] = v1.z; ac11[4*rq+3] = v1.w;
                }
            }

            // ---- 48 MFMAs: each A chunk feeds both point-tiles (4 indep chains)
            #pragma unroll
            for (int q = 0; q < 4; ++q) {
                if (q < 3) {
                    #pragma unroll
                    for (int t = 0; t < 4; ++t) Anx[t] = base[(t * 4 + q + 1) * 64 + lane];
                }
                bf16x8 b0h = asb4(Bhi[0][q][0], Bhi[0][q][1], Bhi[0][q][2], Bhi[0][q][3]);
                bf16x8 b0l = asb4(Blo[0][q][0], Blo[0][q][1], Blo[0][q][2], Blo[0][q][3]);
                bf16x8 b1h = asb4(Bhi[1][q][0], Bhi[1][q][1], Bhi[1][q][2], Bhi[1][q][3]);
                bf16x8 b1l = asb4(Blo[1][q][0], Blo[1][q][1], Blo[1][q][2], Blo[1][q][3]);
                ac00 = MFMA_B(Acur[0], b0h, ac00);   // hi-W x hi-X
                ac01 = MFMA_B(Acur[1], b0h, ac01);
                ac10 = MFMA_B(Acur[0], b1h, ac10);
                ac11 = MFMA_B(Acur[1], b1h, ac11);
                ac00 = MFMA_B(Acur[2], b0h, ac00);   // lo-W x hi-X
                ac01 = MFMA_B(Acur[3], b0h, ac01);
                ac10 = MFMA_B(Acur[2], b1h, ac10);
                ac11 = MFMA_B(Acur[3], b1h, ac11);
                ac00 = MFMA_B(Acur[0], b0l, ac00);   // hi-W x lo-X
                ac01 = MFMA_B(Acur[1], b0l, ac01);
                ac10 = MFMA_B(Acur[0], b1l, ac10);
                ac11 = MFMA_B(Acur[1], b1l, ac11);
                #pragma unroll
                for (int t = 0; t < 4; ++t) Acur[t] = Anx[t];
            }

            __syncthreads();  // all waves done with sA[b]; prefetch of s+1 drained
        }
    }

    // ---- store step-11 output for both tiles
    float* o0 = out + row0;
    float* o1 = out + row1;
    #pragma unroll
    for (int rq = 0; rq < 4; ++rq) {
        const int off = 16 * (rq >> 1) + 8 * h + 4 * (rq & 1);
        float4 v;
        v.x = ac00[4*rq+0]; v.y = ac00[4*rq+1]; v.z = ac00[4*rq+2]; v.w = ac00[4*rq+3];
        *(float4*)(o0 + off) = v;
        v.x = ac01[4*rq+0]; v.y = ac01[4*rq+1]; v.z = ac01[4*rq+2]; v.w = ac01[4*rq+3];
        *(float4*)(o0 + 32 + off) = v;
        v.x = ac10[4*rq+0]; v.y = ac10[4*rq+1]; v.z = ac10[4*rq+2]; v.w = ac10[4*rq+3];
        *(float4*)(o1 + off) = v;
        v.x = ac11[4*rq+0]; v.y = ac11[4*rq+1]; v.z = ac11[4*rq+2]; v.w = ac11[4*rq+3];
        *(float4*)(o1 + 32 + off) = v;
    }
}

extern "C" void kernel_launch(void* const* d_in, const int* in_sizes, int n_in,
                              void* d_out, int out_size, void* d_ws, size_t ws_size,
                              hipStream_t stream) {
    const float* feat = (const float*)d_in[0];
    // d_in[1] = points, d_in[2] = nuv — dead inputs
    const float* W0 = (const float*)d_in[3];
    const float* b0 = (const float*)d_in[4];
    const float* W1 = (const float*)d_in[5];
    const float* b1 = (const float*)d_in[6];
    const float* W2 = (const float*)d_in[7];
    const float* b2 = (const float*)d_in[8];
    float* out = (float*)d_out;
    uint4* wsA = (uint4*)d_ws;   // 12288 * 16B = 192 KiB of scratch

    prep_weights<<<48, 256, 0, stream>>>(W0, W1, W2, wsA);

    const int grid = (NW + WPB - 1) / WPB;
    mlp12_mfma<<<grid, BLK, 0, stream>>>(feat, wsA, b0, b1, b2, out);
}